// Round 18
// baseline (32.076 us; speedup 1.0000x reference)
//
#include <hip/hip_runtime.h>

#define B_SZ     2
#define E_EDGES  16384
#define N_NODES  4096
#define NTOT     (B_SZ * N_NODES)   // 8192 nodes
#define NV       (B_SZ * E_EDGES)   // 32768 edges / queries
#define DVTOT    128
#define LOG2_E   14
#define CAP      32                 // bucket capacity (Poisson(4): P(>=32) ~ 1e-19)

// ws zero region: ecnt[NTOT] qcnt[NTOT] ebuf[NTOT*CAP] int2, qbuf[NTOT*CAP] int
#define ZERO_INT4 200704

// padded LDS index: insert 4-float gap every 16 floats -> head h starts at h*20
__device__ __forceinline__ int padidx(int f) { return f + ((f >> 4) << 2); }

__global__ __launch_bounds__(256) void zero_ws(int4* __restrict__ p) {
    int i = blockIdx.x * blockDim.x + threadIdx.x;
    p[i] = make_int4(0, 0, 0, 0);
}

// 65536 threads: t < NV -> edge-side bucket insert; t >= NV -> query-side.
// One {load -> atomic -> store} chain per thread. Sentinel coding (e+1).
__global__ __launch_bounds__(256) void fill_split(
    const int* __restrict__ qidx,
    const int* __restrict__ vidx,
    int*  __restrict__ ecnt,   // NTOT (cursors only)
    int*  __restrict__ qcnt,   // NTOT (cursors only)
    int2* __restrict__ ebuf,   // NTOT*CAP  {e+1, global key row}
    int*  __restrict__ qbuf)   // NTOT*CAP  (e+1) | (suppress<<31)
{
    int t = blockIdx.x * blockDim.x + threadIdx.x;
    if (t < NV) {
        int e = t;
        int ofs = (e >> LOG2_E) * N_NODES;
        int2 vi = ((const int2*)vidx)[e];
        int col = vi.y + ofs;
        int p = atomicAdd(&ecnt[col], 1);
        if (p < CAP) ebuf[col * CAP + p] = make_int2(e + 1, vi.x + ofs);
    } else {
        int e = t - NV;
        int ofs = (e >> LOG2_E) * N_NODES;
        int2 qi = ((const int2*)qidx)[e];
        int g  = qi.y + ofs;
        int pq = atomicAdd(&qcnt[g], 1);
        if (pq < CAP) qbuf[g * CAP + pq] = (e + 1) | ((qi.x == qi.y) ? 0x80000000 : 0);
    }
}

#define KACC(C, V)                                                       \
    {                                                                    \
        const float4* kp = (const float4*)&sk[wid][C][h20];              \
        float4 k0 = kp[0], k1 = kp[1], k2 = kp[2], k3 = kp[3];           \
        float kk[16] = {k0.x,k0.y,k0.z,k0.w, k1.x,k1.y,k1.z,k1.w,        \
                        k2.x,k2.y,k2.z,k2.w, k3.x,k3.y,k3.z,k3.w};       \
        _Pragma("unroll")                                                \
        for (int i = 0; i < 16; ++i) {                                   \
            ks[i]  += kk[i];                                             \
            kva[i] += kk[i] * (V).x;                                     \
            kvb[i] += kk[i] * (V).y;                                     \
        }                                                                \
    }

#define QOUT(C, TREG)                                                    \
    {                                                                    \
        const float4* qp = (const float4*)&sq[wid][C][h20];              \
        float4 q0 = qp[0], q1 = qp[1], q2 = qp[2], q3 = qp[3];           \
        float qq[16] = {q0.x,q0.y,q0.z,q0.w, q1.x,q1.y,q1.z,q1.w,        \
                        q2.x,q2.y,q2.z,q2.w, q3.x,q3.y,q3.z,q3.w};       \
        float sa = 0.0f, sb = 0.0f, w = 0.0f;                            \
        _Pragma("unroll")                                                \
        for (int i = 0; i < 16; ++i) {                                   \
            sa += qq[i] * kva[i];                                        \
            sb += qq[i] * kvb[i];                                        \
            w  += qq[i] * ks[i];                                         \
        }                                                                \
        float den = (w == 0.0f) ? 1e-5f : w;                             \
        float inv = 1.0f / den;                                          \
        float2 o;                                                        \
        o.x = ((TREG) < 0) ? 0.0f : sa * inv;                            \
        o.y = ((TREG) < 0) ? 0.0f : sb * inv;                            \
        *(float2*)(out + (size_t)(((TREG) & 0x7FFFFFFF) - 1) * DVTOT + f2) = o; \
    }

// One node per WAVE (4 per 256-thread block), no block barriers.
// lane l: head h = l>>3, columns j = 2*(l&7), +1.
// __launch_bounds__(256, 6): cap ~85 VGPR -> 6 blocks/CU (24 waves) if it
// fits without spills; LDS 20KB/block allows up to 8.
__global__ __launch_bounds__(256, 6) void attn_node(
    const float* __restrict__ qv,
    const float* __restrict__ keys,
    const float* __restrict__ vals,
    const int2*  __restrict__ ebuf,
    const int*   __restrict__ qbuf,
    float*       __restrict__ out)
{
    __shared__ float sk[4][4][160];   // [wave][chunk][padded row]
    __shared__ float sq[4][4][160];

    int wid  = threadIdx.x >> 6;
    int lane = threadIdx.x & 63;
    int g    = __builtin_amdgcn_readfirstlane(blockIdx.x * 4 + wid);

    int h20 = (lane >> 3) * 20;
    int f2  = 2 * lane;
    int pf2 = padidx(f2);

    const int2* eb = ebuf + (size_t)g * CAP;
    const int*  qb = qbuf + (size_t)g * CAP;

    // parallel scalar prologue: first 8 records of both buckets (SGPRs)
    int qt[8]; int2 er[8];
#pragma unroll
    for (int c = 0; c < 8; ++c) { qt[c] = qb[c]; er[c] = eb[c]; }

    int nq0 = qt[0] ? (qt[1] ? (qt[2] ? (qt[3] ? 4 : 3) : 2) : 1) : 0;
    if (nq0 == 0) return;                            // wave-uniform
    int dg0 = er[0].x ? (er[1].x ? (er[2].x ? (er[3].x ? 4 : 3) : 2) : 1) : 0;

    // ---- chunk-0 vector loads, unconditional (clamped), back-to-back ----
    float2 vvv[4];
    if (dg0) {
#pragma unroll
        for (int c = 0; c < 4; ++c) {
            int2 rc = (c < dg0) ? er[c] : er[0];
            *(float2*)&sk[wid][c][pf2] =
                *(const float2*)(keys + (size_t)rc.y * DVTOT + f2);
            vvv[c] = *(const float2*)(vals + (size_t)(rc.x - 1) * DVTOT + f2);
        }
    }
#pragma unroll
    for (int c = 0; c < 4; ++c) {
        int tc = (c < nq0) ? qt[c] : qt[0];
        *(float2*)&sq[wid][c][pf2] =
            *(const float2*)(qv + (size_t)((tc & 0x7FFFFFFF) - 1) * DVTOT + f2);
    }
    __builtin_amdgcn_wave_barrier();

    float kva[16], kvb[16], ks[16];
#pragma unroll
    for (int i = 0; i < 16; ++i) { kva[i] = 0.0f; kvb[i] = 0.0f; ks[i] = 0.0f; }

    // ---- chunk-0 k accumulate ----
#pragma unroll
    for (int c = 0; c < 4; ++c)
        if (c < dg0) KACC(c, vvv[c]);

    // ---- k chunk-1: records already in SGPRs (deg 5..8) ----
    if (dg0 == 4) {
        int n1 = er[4].x ? (er[5].x ? (er[6].x ? (er[7].x ? 4 : 3) : 2) : 1) : 0;
        if (n1) {
            float2 vv[4];
#pragma unroll
            for (int c = 0; c < 4; ++c) {
                int2 rc = (c < n1) ? er[4 + c] : er[4];
                vv[c] = *(const float2*)(vals + (size_t)(rc.x - 1) * DVTOT + f2);
            }
            __builtin_amdgcn_wave_barrier();         // WAR on sk
#pragma unroll
            for (int c = 0; c < 4; ++c) {
                int2 rc = (c < n1) ? er[4 + c] : er[4];
                *(float2*)&sk[wid][c][pf2] =
                    *(const float2*)(keys + (size_t)rc.y * DVTOT + f2);
            }
            __builtin_amdgcn_wave_barrier();
#pragma unroll
            for (int c = 0; c < 4; ++c)
                if (c < n1) KACC(c, vv[c]);
            // ---- deep k remainder (deg > 8): probe ----
            if (n1 == 4) {
                for (int base = 8; base < CAP; base += 4) {
                    int2 r[4];
#pragma unroll
                    for (int c = 0; c < 4; ++c) r[c] = eb[base + c];
                    int n = r[0].x ? (r[1].x ? (r[2].x ? (r[3].x ? 4 : 3) : 2) : 1) : 0;
                    if (n == 0) break;
                    float2 vr[4];
#pragma unroll
                    for (int c = 0; c < 4; ++c) {
                        int2 rc = (c < n) ? r[c] : r[0];
                        vr[c] = *(const float2*)(vals + (size_t)(rc.x - 1) * DVTOT + f2);
                    }
                    __builtin_amdgcn_wave_barrier();
#pragma unroll
                    for (int c = 0; c < 4; ++c) {
                        int2 rc = (c < n) ? r[c] : r[0];
                        *(float2*)&sk[wid][c][pf2] =
                            *(const float2*)(keys + (size_t)rc.y * DVTOT + f2);
                    }
                    __builtin_amdgcn_wave_barrier();
#pragma unroll
                    for (int c = 0; c < 4; ++c)
                        if (c < n) KACC(c, vr[c]);
                    if (n < 4) break;
                }
            }
        }
    }

    // ---- q outputs, chunk 0 (rows already staged) ----
#pragma unroll
    for (int c = 0; c < 4; ++c)
        if (c < nq0) QOUT(c, qt[c]);

    // ---- q chunk-1: records already in SGPRs (nq 5..8) ----
    if (nq0 == 4) {
        int n1 = qt[4] ? (qt[5] ? (qt[6] ? (qt[7] ? 4 : 3) : 2) : 1) : 0;
        if (n1) {
            float2 q2[4];
#pragma unroll
            for (int c = 0; c < 4; ++c) {
                int tc = (c < n1) ? qt[4 + c] : qt[4];
                q2[c] = *(const float2*)(qv + (size_t)((tc & 0x7FFFFFFF) - 1) * DVTOT + f2);
            }
            __builtin_amdgcn_wave_barrier();         // WAR on sq
#pragma unroll
            for (int c = 0; c < 4; ++c)
                *(float2*)&sq[wid][c][pf2] = q2[c];
            __builtin_amdgcn_wave_barrier();
#pragma unroll
            for (int c = 0; c < 4; ++c)
                if (c < n1) QOUT(c, qt[4 + c]);
            // ---- deep q remainder (nq > 8): probe ----
            if (n1 == 4) {
                for (int base = 8; base < CAP; base += 4) {
                    int t[4];
#pragma unroll
                    for (int c = 0; c < 4; ++c) t[c] = qb[base + c];
                    int n = t[0] ? (t[1] ? (t[2] ? (t[3] ? 4 : 3) : 2) : 1) : 0;
                    if (n == 0) break;
                    float2 qr[4];
#pragma unroll
                    for (int c = 0; c < 4; ++c) {
                        int tc = (c < n) ? t[c] : t[0];
                        qr[c] = *(const float2*)(qv + (size_t)((tc & 0x7FFFFFFF) - 1) * DVTOT + f2);
                    }
                    __builtin_amdgcn_wave_barrier();
#pragma unroll
                    for (int c = 0; c < 4; ++c)
                        *(float2*)&sq[wid][c][pf2] = qr[c];
                    __builtin_amdgcn_wave_barrier();
#pragma unroll
                    for (int c = 0; c < 4; ++c)
                        if (c < n) QOUT(c, t[c]);
                    if (n < 4) break;
                }
            }
        }
    }
}

extern "C" void kernel_launch(void* const* d_in, const int* in_sizes, int n_in,
                              void* d_out, int out_size, void* d_ws, size_t ws_size,
                              hipStream_t stream) {
    const float* qv   = (const float*)d_in[0];
    const float* keys = (const float*)d_in[1];
    const float* vals = (const float*)d_in[2];
    const int*   qidx = (const int*)d_in[3];
    const int*   vidx = (const int*)d_in[4];
    float* out = (float*)d_out;

    char* ws = (char*)d_ws;
    int*  ecnt = (int*)ws;                                // NTOT
    int*  qcnt = ecnt + NTOT;                             // NTOT
    int2* ebuf = (int2*)(qcnt + NTOT);                    // NTOT*CAP int2
    int*  qbuf = (int*)(ebuf + (size_t)NTOT * CAP);       // NTOT*CAP int

    zero_ws<<<ZERO_INT4 / 256, 256, 0, stream>>>((int4*)ws);
    fill_split<<<(2 * NV) / 256, 256, 0, stream>>>(qidx, vidx, ecnt, qcnt, ebuf, qbuf);
    attn_node<<<NTOT / 4, 256, 0, stream>>>(qv, keys, vals, ebuf, qbuf, out);
}

// Round 19
// 30.790 us; speedup vs baseline: 1.0418x; 1.0418x over previous
//
#include <hip/hip_runtime.h>

#define B_SZ     2
#define E_EDGES  16384
#define N_NODES  4096
#define NTOT     (B_SZ * N_NODES)   // 8192 nodes
#define NV       (B_SZ * E_EDGES)   // 32768 edges / queries
#define DVTOT    128
#define LOG2_E   14
#define CAP      32                 // bucket capacity (Poisson(4): P(>=32) ~ 1e-19)

// ws zero region: ecnt[NTOT] qcnt[NTOT] ebuf[NTOT*CAP] int2, qbuf[NTOT*CAP] int
#define ZERO_INT4 200704

// padded LDS index: insert 4-float gap every 16 floats -> head h starts at h*20
__device__ __forceinline__ int padidx(int f) { return f + ((f >> 4) << 2); }

__global__ __launch_bounds__(256) void zero_ws(int4* __restrict__ p) {
    int i = blockIdx.x * blockDim.x + threadIdx.x;
    p[i] = make_int4(0, 0, 0, 0);
}

// 32768 threads, 2 edges each: t < NV/2 -> edge-side pair; else query-side pair.
// Two INDEPENDENT {atomic -> store} chains per thread (issue in parallel).
__global__ __launch_bounds__(256) void fill_split2(
    const int* __restrict__ qidx,
    const int* __restrict__ vidx,
    int*  __restrict__ ecnt,   // NTOT (cursors only)
    int*  __restrict__ qcnt,   // NTOT (cursors only)
    int2* __restrict__ ebuf,   // NTOT*CAP  {e+1, global key row}
    int*  __restrict__ qbuf)   // NTOT*CAP  (e+1) | (suppress<<31)
{
    int t = blockIdx.x * blockDim.x + threadIdx.x;
    if (t < NV / 2) {
        int e0 = t * 2;
        int ofs = (e0 >> LOG2_E) * N_NODES;          // e0, e0+1 same batch (NV/2 even split)
        int4 vi = ((const int4*)vidx)[t];            // {row0,col0,row1,col1}
        int col0 = vi.y + ofs;
        int col1 = vi.w + ofs;
        int p0 = atomicAdd(&ecnt[col0], 1);
        int p1 = atomicAdd(&ecnt[col1], 1);
        if (p0 < CAP) ebuf[col0 * CAP + p0] = make_int2(e0 + 1, vi.x + ofs);
        if (p1 < CAP) ebuf[col1 * CAP + p1] = make_int2(e0 + 2, vi.z + ofs);
    } else {
        int e0 = (t - NV / 2) * 2;
        int ofs = (e0 >> LOG2_E) * N_NODES;
        int4 qi = ((const int4*)qidx)[t - NV / 2];   // {q00,q01,q10,q11}
        int g0 = qi.y + ofs;
        int g1 = qi.w + ofs;
        int p0 = atomicAdd(&qcnt[g0], 1);
        int p1 = atomicAdd(&qcnt[g1], 1);
        if (p0 < CAP) qbuf[g0 * CAP + p0] = (e0 + 1) | ((qi.x == qi.y) ? 0x80000000 : 0);
        if (p1 < CAP) qbuf[g1 * CAP + p1] = (e0 + 2) | ((qi.z == qi.w) ? 0x80000000 : 0);
    }
}

#define KACC(C, V)                                                       \
    {                                                                    \
        const float4* kp = (const float4*)&sk[wid][C][h20];              \
        float4 k0 = kp[0], k1 = kp[1], k2 = kp[2], k3 = kp[3];           \
        float kk[16] = {k0.x,k0.y,k0.z,k0.w, k1.x,k1.y,k1.z,k1.w,        \
                        k2.x,k2.y,k2.z,k2.w, k3.x,k3.y,k3.z,k3.w};       \
        _Pragma("unroll")                                                \
        for (int i = 0; i < 16; ++i) {                                   \
            ks[i]  += kk[i];                                             \
            kva[i] += kk[i] * (V).x;                                     \
            kvb[i] += kk[i] * (V).y;                                     \
        }                                                                \
    }

#define QOUT(C, TREG)                                                    \
    {                                                                    \
        const float4* qp = (const float4*)&sq[wid][C][h20];              \
        float4 q0 = qp[0], q1 = qp[1], q2 = qp[2], q3 = qp[3];           \
        float qq[16] = {q0.x,q0.y,q0.z,q0.w, q1.x,q1.y,q1.z,q1.w,        \
                        q2.x,q2.y,q2.z,q2.w, q3.x,q3.y,q3.z,q3.w};       \
        float sa = 0.0f, sb = 0.0f, w = 0.0f;                            \
        _Pragma("unroll")                                                \
        for (int i = 0; i < 16; ++i) {                                   \
            sa += qq[i] * kva[i];                                        \
            sb += qq[i] * kvb[i];                                        \
            w  += qq[i] * ks[i];                                         \
        }                                                                \
        float den = (w == 0.0f) ? 1e-5f : w;                             \
        float inv = 1.0f / den;                                          \
        float2 o;                                                        \
        o.x = ((TREG) < 0) ? 0.0f : sa * inv;                            \
        o.y = ((TREG) < 0) ? 0.0f : sb * inv;                            \
        *(float2*)(out + (size_t)(((TREG) & 0x7FFFFFFF) - 1) * DVTOT + f2) = o; \
    }

// One node per WAVE (4 per 256-thread block), no block barriers.
// lane l: head h = l>>3, columns j = 2*(l&7), +1.  (exact R11 kernel)
__global__ __launch_bounds__(256) void attn_node(
    const float* __restrict__ qv,
    const float* __restrict__ keys,
    const float* __restrict__ vals,
    const int2*  __restrict__ ebuf,
    const int*   __restrict__ qbuf,
    float*       __restrict__ out)
{
    __shared__ float sk[4][4][160];   // [wave][chunk][padded row]
    __shared__ float sq[4][4][160];

    int wid  = threadIdx.x >> 6;
    int lane = threadIdx.x & 63;
    int g    = __builtin_amdgcn_readfirstlane(blockIdx.x * 4 + wid);

    int h20 = (lane >> 3) * 20;
    int f2  = 2 * lane;
    int pf2 = padidx(f2);

    const int2* eb = ebuf + (size_t)g * CAP;
    const int*  qb = qbuf + (size_t)g * CAP;

    // parallel scalar prologue: first 8 records of both buckets (SGPRs)
    int qt[8]; int2 er[8];
#pragma unroll
    for (int c = 0; c < 8; ++c) { qt[c] = qb[c]; er[c] = eb[c]; }

    int nq0 = qt[0] ? (qt[1] ? (qt[2] ? (qt[3] ? 4 : 3) : 2) : 1) : 0;
    if (nq0 == 0) return;                            // wave-uniform
    int dg0 = er[0].x ? (er[1].x ? (er[2].x ? (er[3].x ? 4 : 3) : 2) : 1) : 0;

    // ---- chunk-0 vector loads, unconditional (clamped), back-to-back ----
    float2 vvv[4];
    if (dg0) {
#pragma unroll
        for (int c = 0; c < 4; ++c) {
            int2 rc = (c < dg0) ? er[c] : er[0];
            *(float2*)&sk[wid][c][pf2] =
                *(const float2*)(keys + (size_t)rc.y * DVTOT + f2);
            vvv[c] = *(const float2*)(vals + (size_t)(rc.x - 1) * DVTOT + f2);
        }
    }
#pragma unroll
    for (int c = 0; c < 4; ++c) {
        int tc = (c < nq0) ? qt[c] : qt[0];
        *(float2*)&sq[wid][c][pf2] =
            *(const float2*)(qv + (size_t)((tc & 0x7FFFFFFF) - 1) * DVTOT + f2);
    }
    __builtin_amdgcn_wave_barrier();

    float kva[16], kvb[16], ks[16];
#pragma unroll
    for (int i = 0; i < 16; ++i) { kva[i] = 0.0f; kvb[i] = 0.0f; ks[i] = 0.0f; }

    // ---- chunk-0 k accumulate ----
#pragma unroll
    for (int c = 0; c < 4; ++c)
        if (c < dg0) KACC(c, vvv[c]);

    // ---- k chunk-1: records already in SGPRs (deg 5..8) ----
    if (dg0 == 4) {
        int n1 = er[4].x ? (er[5].x ? (er[6].x ? (er[7].x ? 4 : 3) : 2) : 1) : 0;
        if (n1) {
            float2 vv[4];
#pragma unroll
            for (int c = 0; c < 4; ++c) {
                int2 rc = (c < n1) ? er[4 + c] : er[4];
                vv[c] = *(const float2*)(vals + (size_t)(rc.x - 1) * DVTOT + f2);
            }
            __builtin_amdgcn_wave_barrier();         // WAR on sk
#pragma unroll
            for (int c = 0; c < 4; ++c) {
                int2 rc = (c < n1) ? er[4 + c] : er[4];
                *(float2*)&sk[wid][c][pf2] =
                    *(const float2*)(keys + (size_t)rc.y * DVTOT + f2);
            }
            __builtin_amdgcn_wave_barrier();
#pragma unroll
            for (int c = 0; c < 4; ++c)
                if (c < n1) KACC(c, vv[c]);
            // ---- deep k remainder (deg > 8): probe ----
            if (n1 == 4) {
                for (int base = 8; base < CAP; base += 4) {
                    int2 r[4];
#pragma unroll
                    for (int c = 0; c < 4; ++c) r[c] = eb[base + c];
                    int n = r[0].x ? (r[1].x ? (r[2].x ? (r[3].x ? 4 : 3) : 2) : 1) : 0;
                    if (n == 0) break;
                    float2 vr[4];
#pragma unroll
                    for (int c = 0; c < 4; ++c) {
                        int2 rc = (c < n) ? r[c] : r[0];
                        vr[c] = *(const float2*)(vals + (size_t)(rc.x - 1) * DVTOT + f2);
                    }
                    __builtin_amdgcn_wave_barrier();
#pragma unroll
                    for (int c = 0; c < 4; ++c) {
                        int2 rc = (c < n) ? r[c] : r[0];
                        *(float2*)&sk[wid][c][pf2] =
                            *(const float2*)(keys + (size_t)rc.y * DVTOT + f2);
                    }
                    __builtin_amdgcn_wave_barrier();
#pragma unroll
                    for (int c = 0; c < 4; ++c)
                        if (c < n) KACC(c, vr[c]);
                    if (n < 4) break;
                }
            }
        }
    }

    // ---- q outputs, chunk 0 (rows already staged) ----
#pragma unroll
    for (int c = 0; c < 4; ++c)
        if (c < nq0) QOUT(c, qt[c]);

    // ---- q chunk-1: records already in SGPRs (nq 5..8) ----
    if (nq0 == 4) {
        int n1 = qt[4] ? (qt[5] ? (qt[6] ? (qt[7] ? 4 : 3) : 2) : 1) : 0;
        if (n1) {
            float2 q2[4];
#pragma unroll
            for (int c = 0; c < 4; ++c) {
                int tc = (c < n1) ? qt[4 + c] : qt[4];
                q2[c] = *(const float2*)(qv + (size_t)((tc & 0x7FFFFFFF) - 1) * DVTOT + f2);
            }
            __builtin_amdgcn_wave_barrier();         // WAR on sq
#pragma unroll
            for (int c = 0; c < 4; ++c)
                *(float2*)&sq[wid][c][pf2] = q2[c];
            __builtin_amdgcn_wave_barrier();
#pragma unroll
            for (int c = 0; c < 4; ++c)
                if (c < n1) QOUT(c, qt[4 + c]);
            // ---- deep q remainder (nq > 8): probe ----
            if (n1 == 4) {
                for (int base = 8; base < CAP; base += 4) {
                    int t[4];
#pragma unroll
                    for (int c = 0; c < 4; ++c) t[c] = qb[base + c];
                    int n = t[0] ? (t[1] ? (t[2] ? (t[3] ? 4 : 3) : 2) : 1) : 0;
                    if (n == 0) break;
                    float2 qr[4];
#pragma unroll
                    for (int c = 0; c < 4; ++c) {
                        int tc = (c < n) ? t[c] : t[0];
                        qr[c] = *(const float2*)(qv + (size_t)((tc & 0x7FFFFFFF) - 1) * DVTOT + f2);
                    }
                    __builtin_amdgcn_wave_barrier();
#pragma unroll
                    for (int c = 0; c < 4; ++c)
                        *(float2*)&sq[wid][c][pf2] = qr[c];
                    __builtin_amdgcn_wave_barrier();
#pragma unroll
                    for (int c = 0; c < 4; ++c)
                        if (c < n) QOUT(c, t[c]);
                    if (n < 4) break;
                }
            }
        }
    }
}

extern "C" void kernel_launch(void* const* d_in, const int* in_sizes, int n_in,
                              void* d_out, int out_size, void* d_ws, size_t ws_size,
                              hipStream_t stream) {
    const float* qv   = (const float*)d_in[0];
    const float* keys = (const float*)d_in[1];
    const float* vals = (const float*)d_in[2];
    const int*   qidx = (const int*)d_in[3];
    const int*   vidx = (const int*)d_in[4];
    float* out = (float*)d_out;

    char* ws = (char*)d_ws;
    int*  ecnt = (int*)ws;                                // NTOT
    int*  qcnt = ecnt + NTOT;                             // NTOT
    int2* ebuf = (int2*)(qcnt + NTOT);                    // NTOT*CAP int2
    int*  qbuf = (int*)(ebuf + (size_t)NTOT * CAP);       // NTOT*CAP int

    zero_ws<<<ZERO_INT4 / 256, 256, 0, stream>>>((int4*)ws);
    fill_split2<<<NV / 256, 256, 0, stream>>>(qidx, vidx, ecnt, qcnt, ebuf, qbuf);
    attn_node<<<NTOT / 4, 256, 0, stream>>>(qv, keys, vals, ebuf, qbuf, out);
}